// Round 9
// baseline (91.111 us; speedup 1.0000x reference)
//
#include <hip/hip_runtime.h>
#include <math.h>

#define BB  8
#define HH  512
#define WW  512
#define HW  (HH*WW)

#define TSX 32           // tile width
#define TSY 32           // tile height
#define GR  34           // guidance tile (halo 1)
#define GSS 36           // g_sh row stride (u16)
#define GPLANE (GR*GSS)
#define FR  36           // flow tile (halo 2)
#define FPS 37           // f_lds row stride (f32)
#define FPLANE (FR*FPS)

#define WS_GOFF 32768    // G buffer offset in d_ws

typedef __attribute__((ext_vector_type(8))) short  short8;
typedef __attribute__((ext_vector_type(4))) float  float4v;
typedef __attribute__((ext_vector_type(4))) int    int4v;
typedef __attribute__((ext_vector_type(4))) uint   uint4v;
typedef __attribute__((ext_vector_type(2))) uint   uint2v;

#define MFMA16x32(a,b,c) __builtin_amdgcn_mfma_f32_16x16x32_bf16((a),(b),(c),0,0,0)

// launder: force materialization (best-effort anti-remat)
template <typename T>
static __device__ __forceinline__ void keep(T& x) { asm volatile("" : "+v"(x)); }

static __device__ __forceinline__ uint  fu(float f) { return __float_as_uint(f); }
static __device__ __forceinline__ float uf(uint u)  { return __uint_as_float(u); }

static __device__ __forceinline__ ushort f2bf_rne(float f) {
    uint u = fu(f);
    u += 0x7fffu + ((u >> 16) & 1u);
    return (ushort)(u >> 16);
}
static __device__ __forceinline__ void split_rne(float f, ushort& hi, ushort& lo) {
    hi = f2bf_rne(f);
    float r = f - uf((uint)hi << 16);
    lo = f2bf_rne(r);
}

// tap index for conv2 output row position (qr, rr) within a channel (row-permuted
// so combine offsets are compile-time per (mt, r)); -1 = dead row (zero weights)
static __device__ __forceinline__ int tap_kk(int mtodd, int qr, int rr) {
    if (!mtodd) return 5 * qr + rr;       // taps (qr, 0..3)... (qr,0..4) via rr<4 + below
    if (rr == 0) return 5 * qr + 4;       // taps (qr, 4)
    if (rr == 1) return 20 + qr;          // taps (4, qr)
    if (rr == 2 && qr == 3) return 24;    // tap  (4, 4)
    return -1;
}

// ===================== setup: per-lane MFMA params -> ws =====================
// chunks (uint4 ws[chunk*64 + lane]):
//  0..1  a1h[t]  2..3 a1l[t]   conv1 A (16x16x32): row=16t+c, k=8q+i, split hi/lo
//  4..7  a2h[mt]               conv2 A (16x16x32, K-permuted): row=c->tap,
//                              slot 8q+i -> oc = i<4 ? 4q+i : 16+4q+(i-4); RNE bf16
// 12..13 bi1[t]                b1 at conv1 C rows
// 14..17 bi2[mt]               b2 at permuted conv2 C rows (or 0)
// 18..19 off1 int4 x2          guidance gather offsets (u16 units; pad->0)
__global__ __launch_bounds__(64)
void setup_params(const float* __restrict__ w1, const float* __restrict__ b1,
                  const float* __restrict__ w2, const float* __restrict__ b2,
                  uint4v* __restrict__ ws)
{
    const int L = threadIdx.x;
    const int c = L & 15, q = L >> 4;

    #pragma unroll
    for (int t = 0; t < 2; ++t) {
        short8 hi8, lo8;
        #pragma unroll
        for (int i = 0; i < 8; ++i) {
            const int k = 8 * q + i;
            const float f = (k < 27) ? w1[(16 * t + c) * 27 + k] : 0.f;
            ushort h_, l_; split_rne(f, h_, l_);
            hi8[i] = (short)h_; lo8[i] = (short)l_;
        }
        *reinterpret_cast<short8*>(&ws[(0 + t) * 64 + L]) = hi8;
        *reinterpret_cast<short8*>(&ws[(2 + t) * 64 + L]) = lo8;
    }
    #pragma unroll
    for (int mt = 0; mt < 4; ++mt) {
        const int ch = mt >> 1;
        const int kk = tap_kk(mt & 1, c >> 2, c & 3);   // A row = c -> tap
        short8 a8;
        #pragma unroll
        for (int i = 0; i < 8; ++i) {
            const int oc = (i < 4) ? (4 * q + i) : (16 + 4 * q + (i - 4)); // K-perm
            const float f = (kk >= 0) ? w2[(25 * ch + kk) * 32 + oc] : 0.f;
            a8[i] = (short)f2bf_rne(f);
        }
        *reinterpret_cast<short8*>(&ws[(4 + mt) * 64 + L]) = a8;
    }
    #pragma unroll
    for (int t = 0; t < 2; ++t) {
        float4v v;
        #pragma unroll
        for (int r = 0; r < 4; ++r) v[r] = b1[16 * t + 4 * q + r];
        *reinterpret_cast<float4v*>(&ws[(12 + t) * 64 + L]) = v;
    }
    #pragma unroll
    for (int mt = 0; mt < 4; ++mt) {
        const int ch = mt >> 1;
        float4v v;
        #pragma unroll
        for (int r = 0; r < 4; ++r) {
            const int kk = tap_kk(mt & 1, q, r);        // C row = 4q+r -> tap
            v[r] = (kk >= 0) ? b2[25 * ch + kk] : 0.f;
        }
        *reinterpret_cast<float4v*>(&ws[(14 + mt) * 64 + L]) = v;
    }
    #pragma unroll
    for (int hf = 0; hf < 2; ++hf) {
        int4v o;
        #pragma unroll
        for (int i2 = 0; i2 < 4; ++i2) {
            const int k = 8 * q + 4 * hf + i2;
            if (k < 27) {
                const int ic = k / 9, r9 = k - ic * 9;
                o[i2] = ic * GPLANE + (r9 / 3) * GSS + (r9 % 3);
            } else o[i2] = 0;   // garbage read ok: A weight column is zero
        }
        *reinterpret_cast<int4v*>(&ws[(18 + hf) * 64 + L]) = o;
    }
}

// ================== K1: guidance field -> bf16 planes (4 px/thread) ==================
__global__ __launch_bounds__(256)
void guidance_kernel(const float* __restrict__ v0,
                     const float* __restrict__ v2,
                     ushort* __restrict__ G)
{
    const int idx = (blockIdx.x * 256 + threadIdx.x) * 4;
    const int x = idx & (WW - 1);            // multiple of 4
    const int y = (idx >> 9) & (HH - 1);
    const int b = idx >> 18;

    const float* v0b = v0 + (size_t)b * 2 * HW;
    const float* v2b = v2 + (size_t)b * 2 * HW;

    const float4v f0p = *reinterpret_cast<const float4v*>(v0b + y * WW + x);
    const float4v f1p = *reinterpret_cast<const float4v*>(v0b + HW + y * WW + x);

    ushort o0[4], o1[4], o2[4];
    #pragma unroll
    for (int j = 0; j < 4; ++j) {
        const int xj = x + j;
        const float f0 = f0p[j], f1 = f1p[j];
        const float sgx = (-1.0f + xj * (2.0f / (WW - 1))) + f0 * (2.0f / WW);
        const float sgy = (-1.0f + y  * (2.0f / (HH - 1))) + f1 * (2.0f / HH);
        const float ixf = (sgx + 1.0f) * (0.5f * (WW - 1));
        const float iyf = (sgy + 1.0f) * (0.5f * (HH - 1));
        const float x0f = floorf(ixf), y0f = floorf(iyf);
        const int   x0  = (int)x0f,   y0i = (int)y0f;
        const float wx1 = ixf - x0f, wx0 = 1.0f - wx1;
        const float wy1 = iyf - y0f, wy0 = 1.0f - wy1;
        float s0 = 0.f, s1 = 0.f;
        #pragma unroll
        for (int cy = 0; cy < 2; ++cy) {
            const int yy = y0i + cy;
            const float wy = cy ? wy1 : wy0;
            if (yy >= 0 && yy < HH) {
                #pragma unroll
                for (int cx = 0; cx < 2; ++cx) {
                    const int xx = x0 + cx;
                    if (xx >= 0 && xx < WW) {
                        const float wgt = wy * (cx ? wx1 : wx0);
                        const int i2 = yy * WW + xx;
                        s0 = fmaf(wgt, v2b[i2], s0);
                        s1 = fmaf(wgt, v2b[HW + i2], s1);
                    }
                }
            }
        }
        const float fb0 = f0 + s0;
        const float fb1 = f1 + s1;
        const float wv  = __expf(-sqrtf(fmaf(fb0, fb0, fb1 * fb1)));
        o0[j] = f2bf_rne(fb0); o1[j] = f2bf_rne(fb1); o2[j] = f2bf_rne(wv);
    }
    const size_t base = (size_t)b * 3 * HW + y * WW + x;
    uint2v p0 = { (uint)o0[0] | ((uint)o0[1] << 16), (uint)o0[2] | ((uint)o0[3] << 16) };
    uint2v p1 = { (uint)o1[0] | ((uint)o1[1] << 16), (uint)o1[2] | ((uint)o1[3] << 16) };
    uint2v p2 = { (uint)o2[0] | ((uint)o2[1] << 16), (uint)o2[2] | ((uint)o2[3] << 16) };
    *reinterpret_cast<uint2v*>(&G[base])          = p0;
    *reinterpret_cast<uint2v*>(&G[base + HW])     = p1;
    *reinterpret_cast<uint2v*>(&G[base + 2 * HW]) = p2;
}

// ====== K2: convs + combine; conv2 via K-permuted 16x16x32, no bounce ======
__global__ __launch_bounds__(256, 3)
void refine_kernel(const float* __restrict__ v0,
                   const ushort* __restrict__ G,
                   const uint4v* __restrict__ P,
                   float* __restrict__ out)
{
    __shared__ ushort g_sh[3 * GPLANE];           // bf16 guidance tile
    __shared__ float  f_lds[2 * FPLANE];          // flow tile (halo 2)

    const int bx0 = blockIdx.x * TSX;
    const int by0 = blockIdx.y * TSY;
    const int b   = blockIdx.z;
    const int tid = threadIdx.x;
    const int w   = tid >> 6;
    const int L   = tid & 63;
    const int c   = L & 15;
    const int q   = L >> 4;

    const float*  v0b = v0 + (size_t)b * 2 * HW;
    const ushort* Gb  = G + (size_t)b * 3 * HW;

    // ---- per-lane params (loaded once; ~64 VGPR) ----
    short8 a1h[2], a1l[2], a2[4];
    #pragma unroll
    for (int t = 0; t < 2; ++t) {
        a1h[t] = *reinterpret_cast<const short8*>(&P[(0 + t) * 64 + L]); keep(a1h[t]);
        a1l[t] = *reinterpret_cast<const short8*>(&P[(2 + t) * 64 + L]); keep(a1l[t]);
    }
    #pragma unroll
    for (int mt = 0; mt < 4; ++mt) {
        a2[mt] = *reinterpret_cast<const short8*>(&P[(4 + mt) * 64 + L]); keep(a2[mt]);
    }
    float4v bi1[2], bi2[4];
    #pragma unroll
    for (int t = 0; t < 2; ++t) {
        bi1[t] = *reinterpret_cast<const float4v*>(&P[(12 + t) * 64 + L]); keep(bi1[t]);
    }
    #pragma unroll
    for (int mt = 0; mt < 4; ++mt) {
        bi2[mt] = *reinterpret_cast<const float4v*>(&P[(14 + mt) * 64 + L]); keep(bi2[mt]);
    }
    int off1[8];
    #pragma unroll
    for (int hf = 0; hf < 2; ++hf) {
        int4v o = *reinterpret_cast<const int4v*>(&P[(18 + hf) * 64 + L]); keep(o);
        #pragma unroll
        for (int i2 = 0; i2 < 4; ++i2) off1[hf * 4 + i2] = o[i2];
    }

    // ---- stage flow tile (36x36, halo 2) ----
    for (int i = tid; i < FR * FR; i += 256) {
        const int ly = i / FR, lx = i - (i / FR) * FR;
        const int y = by0 - 2 + ly, x = bx0 - 2 + lx;
        float f0 = 0.f, f1 = 0.f;
        if ((unsigned)y < HH && (unsigned)x < WW) {
            f0 = v0b[y * WW + x];
            f1 = v0b[HW + y * WW + x];
        }
        f_lds[ly * FPS + lx]          = f0;
        f_lds[FPLANE + ly * FPS + lx] = f1;
    }
    // ---- stage guidance tile (34x34, halo 1), 3 bf16 planes ----
    for (int i = tid; i < GR * GR; i += 256) {
        const int ly = i / GR, lx = i - (i / GR) * GR;
        const int y = by0 - 1 + ly, x = bx0 - 1 + lx;
        ushort u0 = 0, u1 = 0, u2 = 0;
        if ((unsigned)y < HH && (unsigned)x < WW) {
            const size_t gi = (size_t)y * WW + x;
            u0 = Gb[gi];
            u1 = Gb[gi + HW];
            u2 = Gb[gi + 2 * HW];
        }
        g_sh[ly * GSS + lx]              = u0;
        g_sh[GPLANE + ly * GSS + lx]     = u1;
        g_sh[2 * GPLANE + ly * GSS + lx] = u2;
    }
    __syncthreads();

    // ---- 16 groups of 16 px per wave: rows 8w..8w+7, halves 0/1 ----
    #pragma unroll 2
    for (int g = 0; g < 16; ++g) {
        const int py = 8 * w + (g >> 1);
        const int px = 16 * (g & 1) + c;
        const int gb = py * GSS + px;

        // B1 frag: 8 bf16 gathers
        short8 b1;
        #pragma unroll
        for (int i = 0; i < 8; ++i) b1[i] = (short)g_sh[off1[i] + gb];

        // conv3x3 GEMM (bf16 B, split A), bias in C
        float4v acc1_0 = bi1[0], acc1_1 = bi1[1];
        acc1_0 = MFMA16x32(a1l[0], b1, acc1_0);
        acc1_0 = MFMA16x32(a1h[0], b1, acc1_0);
        acc1_1 = MFMA16x32(a1l[1], b1, acc1_1);
        acc1_1 = MFMA16x32(a1h[1], b1, acc1_1);

        // ReLU + truncation split -> K-permuted conv2 B frags, in registers:
        // B slot 8q+i holds h[oc=perm(8q+i)] = {acc1_0[i] | acc1_1[i-4]}
        short8 b2h, b2l;
        #pragma unroll
        for (int r = 0; r < 4; ++r) {
            const float h0 = fmaxf(acc1_0[r], 0.f);
            const float h1 = fmaxf(acc1_1[r], 0.f);
            const uint  u0 = fu(h0) & 0xFFFF0000u;
            const uint  u1 = fu(h1) & 0xFFFF0000u;
            b2h[r]     = (short)(u0 >> 16);
            b2h[4 + r] = (short)(u1 >> 16);
            b2l[r]     = (short)(fu(h0 - uf(u0)) >> 16);   // exact residual, trunc
            b2l[4 + r] = (short)(fu(h1 - uf(u1)) >> 16);
        }

        // conv1x1 GEMM via K-permuted 16x16x32: w2h*(h_hi) + w2h*(h_lo)
        float4v acc2[4] = {bi2[0], bi2[1], bi2[2], bi2[3]};
        #pragma unroll
        for (int mt = 0; mt < 4; ++mt) {
            acc2[mt] = MFMA16x32(a2[mt], b2h, acc2[mt]);
            acc2[mt] = MFMA16x32(a2[mt], b2l, acc2[mt]);
        }

        // combine: compile-time tap offsets (row-permuted conv2 output)
        const int pyb   = py * FPS + px;
        const int base0 = pyb + q * FPS;          // taps (q, 0..4)
        const int b4    = pyb + 4 * FPS + q;      // tap  (4, q)
        const int base1 = base0 + FPLANE;
        const int b41   = b4 + FPLANE;

        float s0 = 0.f, s1 = 0.f;
        s0 = fmaf(acc2[0][0], f_lds[base0],      s0);
        s0 = fmaf(acc2[0][1], f_lds[base0 + 1],  s0);
        s0 = fmaf(acc2[0][2], f_lds[base0 + 2],  s0);
        s0 = fmaf(acc2[0][3], f_lds[base0 + 3],  s0);
        s0 = fmaf(acc2[1][0], f_lds[base0 + 4],  s0);
        s0 = fmaf(acc2[1][1], f_lds[b4],         s0);
        s0 = fmaf(acc2[1][2], f_lds[base0 + 41], s0);   // (4,4): kern==0 unless q==3
        s1 = fmaf(acc2[2][0], f_lds[base1],      s1);
        s1 = fmaf(acc2[2][1], f_lds[base1 + 1],  s1);
        s1 = fmaf(acc2[2][2], f_lds[base1 + 2],  s1);
        s1 = fmaf(acc2[2][3], f_lds[base1 + 3],  s1);
        s1 = fmaf(acc2[3][0], f_lds[base1 + 4],  s1);
        s1 = fmaf(acc2[3][1], f_lds[b41],        s1);
        s1 = fmaf(acc2[3][2], f_lds[base1 + 41], s1);

        s0 += __shfl_xor(s0, 16);
        s0 += __shfl_xor(s0, 32);
        s1 += __shfl_xor(s1, 16);
        s1 += __shfl_xor(s1, 32);

        if (q == 0) {
            const int y = by0 + py, x = bx0 + px;
            out[((size_t)b * 2 + 0) * HW + y * WW + x] = s0;
            out[((size_t)b * 2 + 1) * HW + y * WW + x] = s1;
        }
    }
}

extern "C" void kernel_launch(void* const* d_in, const int* in_sizes, int n_in,
                              void* d_out, int out_size, void* d_ws, size_t ws_size,
                              hipStream_t stream) {
    const float* v0 = (const float*)d_in[0];
    const float* v2 = (const float*)d_in[1];
    const float* w1 = (const float*)d_in[2];
    const float* b1 = (const float*)d_in[3];
    const float* w2 = (const float*)d_in[4];
    const float* b2 = (const float*)d_in[5];
    uint4v* ws = (uint4v*)d_ws;
    ushort* G  = (ushort*)((char*)d_ws + WS_GOFF);

    setup_params<<<1, 64, 0, stream>>>(w1, b1, w2, b2, ws);
    guidance_kernel<<<(BB * HW) / 1024, 256, 0, stream>>>(v0, v2, G);

    dim3 grid(WW / TSX, HH / TSY, BB);
    refine_kernel<<<grid, dim3(256, 1, 1), 0, stream>>>(v0, G, ws, (float*)d_out);
}

// Round 10
// 73.677 us; speedup vs baseline: 1.2366x; 1.2366x over previous
//
#include <hip/hip_runtime.h>
#include <math.h>

#define BB  8
#define HH  512
#define WW  512
#define HW  (HH*WW)

#define TSX 32           // tile width
#define TSY 32           // tile height
#define GR  34           // guidance tile (halo 1)
#define GS2 36           // packed guidance row stride (u32 words)
#define FBWORDS (GR*GS2) // fb-plane words (w-plane follows)
#define FR  36           // flow tile (halo 2)
#define FPS 37           // f_lds row stride (f32)
#define FPLANE (FR*FPS)

#define WS_GOFF 32768                     // FB plane (u32[B*HW]) offset in d_ws
#define WS_WOFF (WS_GOFF + BB*HW*4)       // W plane (u16[B*HW])

typedef __attribute__((ext_vector_type(8))) short  short8;
typedef __attribute__((ext_vector_type(4))) float  float4v;
typedef __attribute__((ext_vector_type(4))) int    int4v;
typedef __attribute__((ext_vector_type(4))) uint   uint4v;

#define MFMA16x32(a,b,c) __builtin_amdgcn_mfma_f32_16x16x32_bf16((a),(b),(c),0,0,0)

// launder: force materialization (anti-remat)
template <typename T>
static __device__ __forceinline__ void keep(T& x) { asm volatile("" : "+v"(x)); }

static __device__ __forceinline__ uint  fu(float f) { return __float_as_uint(f); }
static __device__ __forceinline__ float uf(uint u)  { return __uint_as_float(u); }

static __device__ __forceinline__ ushort f2bf_rne(float f) {
    uint u = fu(f);
    u += 0x7fffu + ((u >> 16) & 1u);
    return (ushort)(u >> 16);
}
static __device__ __forceinline__ void split_rne(float f, ushort& hi, ushort& lo) {
    hi = f2bf_rne(f);
    float r = f - uf((uint)hi << 16);
    lo = f2bf_rne(r);
}

// conv2 row-permutation tap (unchanged, verified r7-r9)
static __device__ __forceinline__ int tap_kk(int mtodd, int qr, int rr) {
    if (!mtodd) return 5 * qr + rr;
    if (rr == 0) return 5 * qr + 4;
    if (rr == 1) return 20 + qr;
    if (rr == 2 && qr == 3) return 24;
    return -1;
}

// conv1 K-slot -> original k (27 = ic*9 + (ky*3+kx)), pair-packed scheme:
//  pair p = 4q + (i>>1), elem e = i&1
//  p 0..8  : FB word at tap p        -> k = e ? 9+p : p      (ic = e)
//  p 9..11 : W row word (ky=p-9,kx0) -> k = 18 + 3*(p-9) + e (taps kx=0,1)
//  p 12..14: W word (ky=p-12,kx=2)   -> e==0: k = 18+3*(p-12)+2 ; e==1: dead
//  p 15    : dead pad
static __device__ __forceinline__ int slot_k(int q, int i) {
    const int p = 4 * q + (i >> 1), e = i & 1;
    if (p <= 8)  return e ? 9 + p : p;
    if (p <= 11) return 18 + 3 * (p - 9) + e;
    if (p <= 14) return e ? -1 : 18 + 3 * (p - 12) + 2;
    return -1;
}

// ===================== setup: per-lane MFMA params -> ws =====================
// chunks (uint4 ws[chunk*64 + lane]):
//  0..1 a1h[t]  2..3 a1l[t]   conv1 A, slot-mapped per slot_k
//  4..7 a2[mt]                conv2 A (K-permuted oc), RNE bf16
// 12..13 bi1[t]  14..17 bi2[mt]
// 18 off1 int4               4 word-offsets into g32 (fb plane | w plane)
__global__ __launch_bounds__(64)
void setup_params(const float* __restrict__ w1, const float* __restrict__ b1,
                  const float* __restrict__ w2, const float* __restrict__ b2,
                  uint4v* __restrict__ ws)
{
    const int L = threadIdx.x;
    const int c = L & 15, q = L >> 4;

    #pragma unroll
    for (int t = 0; t < 2; ++t) {
        short8 hi8, lo8;
        #pragma unroll
        for (int i = 0; i < 8; ++i) {
            const int k = slot_k(q, i);
            const float f = (k >= 0) ? w1[(16 * t + c) * 27 + k] : 0.f;
            ushort h_, l_; split_rne(f, h_, l_);
            hi8[i] = (short)h_; lo8[i] = (short)l_;
        }
        *reinterpret_cast<short8*>(&ws[(0 + t) * 64 + L]) = hi8;
        *reinterpret_cast<short8*>(&ws[(2 + t) * 64 + L]) = lo8;
    }
    #pragma unroll
    for (int mt = 0; mt < 4; ++mt) {
        const int ch = mt >> 1;
        const int kk = tap_kk(mt & 1, c >> 2, c & 3);
        short8 a8;
        #pragma unroll
        for (int i = 0; i < 8; ++i) {
            const int oc = (i < 4) ? (4 * q + i) : (16 + 4 * q + (i - 4));
            const float f = (kk >= 0) ? w2[(25 * ch + kk) * 32 + oc] : 0.f;
            a8[i] = (short)f2bf_rne(f);
        }
        *reinterpret_cast<short8*>(&ws[(4 + mt) * 64 + L]) = a8;
    }
    #pragma unroll
    for (int t = 0; t < 2; ++t) {
        float4v v;
        #pragma unroll
        for (int r = 0; r < 4; ++r) v[r] = b1[16 * t + 4 * q + r];
        *reinterpret_cast<float4v*>(&ws[(12 + t) * 64 + L]) = v;
    }
    #pragma unroll
    for (int mt = 0; mt < 4; ++mt) {
        const int ch = mt >> 1;
        float4v v;
        #pragma unroll
        for (int r = 0; r < 4; ++r) {
            const int kk = tap_kk(mt & 1, q, r);
            v[r] = (kk >= 0) ? b2[25 * ch + kk] : 0.f;
        }
        *reinterpret_cast<float4v*>(&ws[(14 + mt) * 64 + L]) = v;
    }
    {
        int4v o;
        #pragma unroll
        for (int pl = 0; pl < 4; ++pl) {
            const int p = 4 * q + pl;
            int off;
            if (p <= 8)       off = (p / 3) * GS2 + (p % 3);                 // FB word
            else if (p <= 11) off = FBWORDS + (p - 9) * GS2;                 // W (ky,0)
            else if (p <= 14) off = FBWORDS + (p - 12) * GS2 + 2;            // W (ky,2)
            else              off = FBWORDS;                                 // pad (dead)
            o[pl] = off;
        }
        *reinterpret_cast<int4v*>(&ws[18 * 64 + L]) = o;
    }
}

// ================== K1: guidance, 1 px/thread (gather-friendly) ==================
__global__ __launch_bounds__(256)
void guidance_kernel(const float* __restrict__ v0,
                     const float* __restrict__ v2,
                     uint* __restrict__ GFB, ushort* __restrict__ GW)
{
    const int idx = blockIdx.x * 256 + threadIdx.x;
    const int x = idx & (WW - 1);
    const int y = (idx >> 9) & (HH - 1);
    const int b = idx >> 18;

    const float* v0b = v0 + (size_t)b * 2 * HW;
    const float* v2b = v2 + (size_t)b * 2 * HW;

    const float f0 = v0b[y * WW + x];
    const float f1 = v0b[HW + y * WW + x];

    const float sgx = (-1.0f + x * (2.0f / (WW - 1))) + f0 * (2.0f / WW);
    const float sgy = (-1.0f + y * (2.0f / (HH - 1))) + f1 * (2.0f / HH);
    const float ixf = (sgx + 1.0f) * (0.5f * (WW - 1));
    const float iyf = (sgy + 1.0f) * (0.5f * (HH - 1));
    const float x0f = floorf(ixf), y0f = floorf(iyf);
    const int   x0  = (int)x0f,   y0i = (int)y0f;
    const float wx1 = ixf - x0f, wx0 = 1.0f - wx1;
    const float wy1 = iyf - y0f, wy0 = 1.0f - wy1;
    float s0 = 0.f, s1 = 0.f;
    #pragma unroll
    for (int cy = 0; cy < 2; ++cy) {
        const int yy = y0i + cy;
        const float wy = cy ? wy1 : wy0;
        if (yy >= 0 && yy < HH) {
            #pragma unroll
            for (int cx = 0; cx < 2; ++cx) {
                const int xx = x0 + cx;
                if (xx >= 0 && xx < WW) {
                    const float wgt = wy * (cx ? wx1 : wx0);
                    const int i2 = yy * WW + xx;
                    s0 = fmaf(wgt, v2b[i2], s0);
                    s1 = fmaf(wgt, v2b[HW + i2], s1);
                }
            }
        }
    }
    const float fb0 = f0 + s0;
    const float fb1 = f1 + s1;
    const float wv  = __expf(-sqrtf(fmaf(fb0, fb0, fb1 * fb1)));

    const size_t base = (size_t)b * HW + y * WW + x;
    GFB[base] = (uint)f2bf_rne(fb0) | ((uint)f2bf_rne(fb1) << 16);
    GW[base]  = f2bf_rne(wv);
}

// ====== K2: convs + combine; pair-packed B1 gather (4 ds_read_b32) ======
__global__ __launch_bounds__(256, 3)
void refine_kernel(const float* __restrict__ v0,
                   const uint* __restrict__ GFB,
                   const ushort* __restrict__ GW,
                   const uint4v* __restrict__ P,
                   float* __restrict__ out)
{
    __shared__ uint  g32[2 * FBWORDS];            // fb-pair plane | w-pair plane
    __shared__ float f_lds[2 * FPLANE];           // flow tile (halo 2)

    const int bx0 = blockIdx.x * TSX;
    const int by0 = blockIdx.y * TSY;
    const int b   = blockIdx.z;
    const int tid = threadIdx.x;
    const int w   = tid >> 6;
    const int L   = tid & 63;
    const int c   = L & 15;
    const int q   = L >> 4;

    const float*  v0b  = v0 + (size_t)b * 2 * HW;
    const uint*   GFBb = GFB + (size_t)b * HW;
    const ushort* GWb  = GW + (size_t)b * HW;

    // ---- per-lane params (loaded once) ----
    short8 a1h[2], a1l[2], a2[4];
    #pragma unroll
    for (int t = 0; t < 2; ++t) {
        a1h[t] = *reinterpret_cast<const short8*>(&P[(0 + t) * 64 + L]); keep(a1h[t]);
        a1l[t] = *reinterpret_cast<const short8*>(&P[(2 + t) * 64 + L]); keep(a1l[t]);
    }
    #pragma unroll
    for (int mt = 0; mt < 4; ++mt) {
        a2[mt] = *reinterpret_cast<const short8*>(&P[(4 + mt) * 64 + L]); keep(a2[mt]);
    }
    float4v bi1[2], bi2[4];
    #pragma unroll
    for (int t = 0; t < 2; ++t) {
        bi1[t] = *reinterpret_cast<const float4v*>(&P[(12 + t) * 64 + L]); keep(bi1[t]);
    }
    #pragma unroll
    for (int mt = 0; mt < 4; ++mt) {
        bi2[mt] = *reinterpret_cast<const float4v*>(&P[(14 + mt) * 64 + L]); keep(bi2[mt]);
    }
    int off1[4];
    {
        int4v o = *reinterpret_cast<const int4v*>(&P[18 * 64 + L]); keep(o);
        #pragma unroll
        for (int pl = 0; pl < 4; ++pl) off1[pl] = o[pl];
    }

    // ---- stage flow tile (36x36, halo 2) ----
    for (int i = tid; i < FR * FR; i += 256) {
        const int ly = i / FR, lx = i - (i / FR) * FR;
        const int y = by0 - 2 + ly, x = bx0 - 2 + lx;
        float f0 = 0.f, f1 = 0.f;
        if ((unsigned)y < HH && (unsigned)x < WW) {
            f0 = v0b[y * WW + x];
            f1 = v0b[HW + y * WW + x];
        }
        f_lds[ly * FPS + lx]          = f0;
        f_lds[FPLANE + ly * FPS + lx] = f1;
    }
    // ---- stage packed guidance: fb words + w pair-words ----
    for (int i = tid; i < GR * GR; i += 256) {
        const int r = i / GR, cc = i - (i / GR) * GR;
        const int y = by0 - 1 + r;
        const int xl = bx0 - 1 + cc;          // fb word / w low element
        uint fbw = 0u, wl = 0u, wr = 0u;
        if ((unsigned)y < HH) {
            const size_t row = (size_t)y * WW;
            if ((unsigned)xl < WW) {
                fbw = GFBb[row + xl];
                wl  = GWb[row + xl];
            }
            const int xr = xl + 1;
            if ((unsigned)xr < WW) wr = GWb[row + xr];
        }
        g32[r * GS2 + cc]           = fbw;
        g32[FBWORDS + r * GS2 + cc] = wl | (wr << 16);
    }
    __syncthreads();

    // ---- 16 groups of 16 px per wave ----
    #pragma unroll 2
    for (int g = 0; g < 16; ++g) {
        const int py = 8 * w + (g >> 1);
        const int px = 16 * (g & 1) + c;
        const int gb = py * GS2 + px;

        // B1 frag: 4 u32 word gathers -> short8 (zero repack)
        uint4v uw;
        #pragma unroll
        for (int pl = 0; pl < 4; ++pl) uw[pl] = g32[off1[pl] + gb];
        const short8 b1 = *reinterpret_cast<const short8*>(&uw);

        // conv3x3 GEMM (bf16 B, split A), bias in C
        float4v acc1_0 = bi1[0], acc1_1 = bi1[1];
        acc1_0 = MFMA16x32(a1l[0], b1, acc1_0);
        acc1_0 = MFMA16x32(a1h[0], b1, acc1_0);
        acc1_1 = MFMA16x32(a1l[1], b1, acc1_1);
        acc1_1 = MFMA16x32(a1h[1], b1, acc1_1);

        // ReLU + truncation split -> K-permuted conv2 B frags (in registers)
        short8 b2h, b2l;
        #pragma unroll
        for (int r = 0; r < 4; ++r) {
            const float h0 = fmaxf(acc1_0[r], 0.f);
            const float h1 = fmaxf(acc1_1[r], 0.f);
            const uint  u0 = fu(h0) & 0xFFFF0000u;
            const uint  u1 = fu(h1) & 0xFFFF0000u;
            b2h[r]     = (short)(u0 >> 16);
            b2h[4 + r] = (short)(u1 >> 16);
            b2l[r]     = (short)(fu(h0 - uf(u0)) >> 16);
            b2l[4 + r] = (short)(fu(h1 - uf(u1)) >> 16);
        }

        // conv1x1 GEMM via K-permuted 16x16x32
        float4v acc2[4] = {bi2[0], bi2[1], bi2[2], bi2[3]};
        #pragma unroll
        for (int mt = 0; mt < 4; ++mt) {
            acc2[mt] = MFMA16x32(a2[mt], b2h, acc2[mt]);
            acc2[mt] = MFMA16x32(a2[mt], b2l, acc2[mt]);
        }

        // combine: compile-time tap offsets (row-permuted conv2 output)
        const int pyb   = py * FPS + px;
        const int base0 = pyb + q * FPS;          // taps (q, 0..4)
        const int b4    = pyb + 4 * FPS + q;      // tap  (4, q)
        const int base1 = base0 + FPLANE;
        const int b41   = b4 + FPLANE;

        float s0 = 0.f, s1 = 0.f;
        s0 = fmaf(acc2[0][0], f_lds[base0],      s0);
        s0 = fmaf(acc2[0][1], f_lds[base0 + 1],  s0);
        s0 = fmaf(acc2[0][2], f_lds[base0 + 2],  s0);
        s0 = fmaf(acc2[0][3], f_lds[base0 + 3],  s0);
        s0 = fmaf(acc2[1][0], f_lds[base0 + 4],  s0);
        s0 = fmaf(acc2[1][1], f_lds[b4],         s0);
        s0 = fmaf(acc2[1][2], f_lds[base0 + 41], s0);   // (4,4): kern==0 unless q==3
        s1 = fmaf(acc2[2][0], f_lds[base1],      s1);
        s1 = fmaf(acc2[2][1], f_lds[base1 + 1],  s1);
        s1 = fmaf(acc2[2][2], f_lds[base1 + 2],  s1);
        s1 = fmaf(acc2[2][3], f_lds[base1 + 3],  s1);
        s1 = fmaf(acc2[3][0], f_lds[base1 + 4],  s1);
        s1 = fmaf(acc2[3][1], f_lds[b41],        s1);
        s1 = fmaf(acc2[3][2], f_lds[base1 + 41], s1);

        s0 += __shfl_xor(s0, 16);
        s0 += __shfl_xor(s0, 32);
        s1 += __shfl_xor(s1, 16);
        s1 += __shfl_xor(s1, 32);

        if (q == 0) {
            const int y = by0 + py, x = bx0 + px;
            out[((size_t)b * 2 + 0) * HW + y * WW + x] = s0;
            out[((size_t)b * 2 + 1) * HW + y * WW + x] = s1;
        }
    }
}

extern "C" void kernel_launch(void* const* d_in, const int* in_sizes, int n_in,
                              void* d_out, int out_size, void* d_ws, size_t ws_size,
                              hipStream_t stream) {
    const float* v0 = (const float*)d_in[0];
    const float* v2 = (const float*)d_in[1];
    const float* w1 = (const float*)d_in[2];
    const float* b1 = (const float*)d_in[3];
    const float* w2 = (const float*)d_in[4];
    const float* b2 = (const float*)d_in[5];
    uint4v* ws  = (uint4v*)d_ws;
    uint*   GFB = (uint*)((char*)d_ws + WS_GOFF);
    ushort* GW  = (ushort*)((char*)d_ws + WS_WOFF);

    setup_params<<<1, 64, 0, stream>>>(w1, b1, w2, b2, ws);
    guidance_kernel<<<(BB * HW) / 256, 256, 0, stream>>>(v0, v2, GFB, GW);

    dim3 grid(WW / TSX, HH / TSY, BB);
    refine_kernel<<<grid, dim3(256, 1, 1), 0, stream>>>(v0, GFB, GW, ws, (float*)d_out);
}

// Round 11
// 66.006 us; speedup vs baseline: 1.3803x; 1.1162x over previous
//
#include <hip/hip_runtime.h>
#include <math.h>

#define BB  8
#define HH  512
#define WW  512
#define HW  (HH*WW)

#define TSX 32           // tile width
#define TSY 32           // tile height
#define GR  34           // guidance tile (halo 1)
#define GS2 36           // packed guidance row stride (u32 words)
#define FBWORDS (GR*GS2) // fb-plane words (w-plane follows)
#define FR  36           // flow tile (halo 2)
#define FPS2 37          // flow row stride (float2 units)

#define WS_GOFF 32768                     // FB plane (u32[B*HW]) offset in d_ws
#define WS_WOFF (WS_GOFF + BB*HW*4)       // W plane (u16[B*HW])

typedef __attribute__((ext_vector_type(8))) short  short8;
typedef __attribute__((ext_vector_type(4))) float  float4v;
typedef __attribute__((ext_vector_type(2))) float  float2v;
typedef __attribute__((ext_vector_type(4))) int    int4v;
typedef __attribute__((ext_vector_type(4))) uint   uint4v;

#define MFMA16x32(a,b,c) __builtin_amdgcn_mfma_f32_16x16x32_bf16((a),(b),(c),0,0,0)

// launder: force materialization (anti-remat)
template <typename T>
static __device__ __forceinline__ void keep(T& x) { asm volatile("" : "+v"(x)); }

static __device__ __forceinline__ uint  fu(float f) { return __float_as_uint(f); }
static __device__ __forceinline__ float uf(uint u)  { return __uint_as_float(u); }

static __device__ __forceinline__ ushort f2bf_rne(float f) {
    uint u = fu(f);
    u += 0x7fffu + ((u >> 16) & 1u);
    return (ushort)(u >> 16);
}
static __device__ __forceinline__ void split_rne(float f, ushort& hi, ushort& lo) {
    hi = f2bf_rne(f);
    float r = f - uf((uint)hi << 16);
    lo = f2bf_rne(r);
}

// conv2 row-permutation tap (verified r7-r10)
static __device__ __forceinline__ int tap_kk(int mtodd, int qr, int rr) {
    if (!mtodd) return 5 * qr + rr;
    if (rr == 0) return 5 * qr + 4;
    if (rr == 1) return 20 + qr;
    if (rr == 2 && qr == 3) return 24;
    return -1;
}

// conv1 K-slot -> original k (pair-packed scheme, verified r10)
static __device__ __forceinline__ int slot_k(int q, int i) {
    const int p = 4 * q + (i >> 1), e = i & 1;
    if (p <= 8)  return e ? 9 + p : p;
    if (p <= 11) return 18 + 3 * (p - 9) + e;
    if (p <= 14) return e ? -1 : 18 + 3 * (p - 12) + 2;
    return -1;
}

// ===================== setup: per-lane MFMA params -> ws =====================
// chunks (uint4 ws[chunk*64 + lane]):
//  0..1 a1h[t]  2..3 a1l[t]   conv1 A, slot-mapped per slot_k, split hi/lo
//  4..7 a2[mt]                conv2 A (K-permuted oc), RNE bf16
// 12..13 bi1[t]  14..17 bi2[mt]
// 18 off1 int4               4 word-offsets into g32 (fb plane | w plane)
__global__ __launch_bounds__(64)
void setup_params(const float* __restrict__ w1, const float* __restrict__ b1,
                  const float* __restrict__ w2, const float* __restrict__ b2,
                  uint4v* __restrict__ ws)
{
    const int L = threadIdx.x;
    const int c = L & 15, q = L >> 4;

    #pragma unroll
    for (int t = 0; t < 2; ++t) {
        short8 hi8, lo8;
        #pragma unroll
        for (int i = 0; i < 8; ++i) {
            const int k = slot_k(q, i);
            const float f = (k >= 0) ? w1[(16 * t + c) * 27 + k] : 0.f;
            ushort h_, l_; split_rne(f, h_, l_);
            hi8[i] = (short)h_; lo8[i] = (short)l_;
        }
        *reinterpret_cast<short8*>(&ws[(0 + t) * 64 + L]) = hi8;
        *reinterpret_cast<short8*>(&ws[(2 + t) * 64 + L]) = lo8;
    }
    #pragma unroll
    for (int mt = 0; mt < 4; ++mt) {
        const int ch = mt >> 1;
        const int kk = tap_kk(mt & 1, c >> 2, c & 3);
        short8 a8;
        #pragma unroll
        for (int i = 0; i < 8; ++i) {
            const int oc = (i < 4) ? (4 * q + i) : (16 + 4 * q + (i - 4));
            const float f = (kk >= 0) ? w2[(25 * ch + kk) * 32 + oc] : 0.f;
            a8[i] = (short)f2bf_rne(f);
        }
        *reinterpret_cast<short8*>(&ws[(4 + mt) * 64 + L]) = a8;
    }
    #pragma unroll
    for (int t = 0; t < 2; ++t) {
        float4v v;
        #pragma unroll
        for (int r = 0; r < 4; ++r) v[r] = b1[16 * t + 4 * q + r];
        *reinterpret_cast<float4v*>(&ws[(12 + t) * 64 + L]) = v;
    }
    #pragma unroll
    for (int mt = 0; mt < 4; ++mt) {
        const int ch = mt >> 1;
        float4v v;
        #pragma unroll
        for (int r = 0; r < 4; ++r) {
            const int kk = tap_kk(mt & 1, q, r);
            v[r] = (kk >= 0) ? b2[25 * ch + kk] : 0.f;
        }
        *reinterpret_cast<float4v*>(&ws[(14 + mt) * 64 + L]) = v;
    }
    {
        int4v o;
        #pragma unroll
        for (int pl = 0; pl < 4; ++pl) {
            const int p = 4 * q + pl;
            int off;
            if (p <= 8)       off = (p / 3) * GS2 + (p % 3);        // FB word
            else if (p <= 11) off = FBWORDS + (p - 9) * GS2;        // W (ky,0)
            else if (p <= 14) off = FBWORDS + (p - 12) * GS2 + 2;   // W (ky,2)
            else              off = FBWORDS;                        // pad (dead)
            o[pl] = off;
        }
        *reinterpret_cast<int4v*>(&ws[18 * 64 + L]) = o;
    }
}

// ============ K1: guidance, 1 px/thread, 2-row x 128-col blocks ============
__global__ __launch_bounds__(256)
void guidance_kernel(const float* __restrict__ v0,
                     const float* __restrict__ v2,
                     uint* __restrict__ GFB, ushort* __restrict__ GW)
{
    const int tid = threadIdx.x;
    const int bx  = blockIdx.x;
    const int x   = (bx & 3) * 128 + (tid & 127);
    const int yy  = (bx >> 2) * 2 + (tid >> 7);
    const int y   = yy & (HH - 1);
    const int b   = yy >> 9;

    const float* v0b = v0 + (size_t)b * 2 * HW;
    const float* v2b = v2 + (size_t)b * 2 * HW;

    const float f0 = v0b[y * WW + x];
    const float f1 = v0b[HW + y * WW + x];

    const float sgx = (-1.0f + x * (2.0f / (WW - 1))) + f0 * (2.0f / WW);
    const float sgy = (-1.0f + y * (2.0f / (HH - 1))) + f1 * (2.0f / HH);
    const float ixf = (sgx + 1.0f) * (0.5f * (WW - 1));
    const float iyf = (sgy + 1.0f) * (0.5f * (HH - 1));
    const float x0f = floorf(ixf), y0f = floorf(iyf);
    const int   x0  = (int)x0f,   y0i = (int)y0f;
    const float wx1 = ixf - x0f, wx0 = 1.0f - wx1;
    const float wy1 = iyf - y0f, wy0 = 1.0f - wy1;
    float s0 = 0.f, s1 = 0.f;
    #pragma unroll
    for (int cy = 0; cy < 2; ++cy) {
        const int yc = y0i + cy;
        const float wy = cy ? wy1 : wy0;
        if (yc >= 0 && yc < HH) {
            #pragma unroll
            for (int cx = 0; cx < 2; ++cx) {
                const int xc = x0 + cx;
                if (xc >= 0 && xc < WW) {
                    const float wgt = wy * (cx ? wx1 : wx0);
                    const int i2 = yc * WW + xc;
                    s0 = fmaf(wgt, v2b[i2], s0);
                    s1 = fmaf(wgt, v2b[HW + i2], s1);
                }
            }
        }
    }
    const float fb0 = f0 + s0;
    const float fb1 = f1 + s1;
    const float wv  = __expf(-sqrtf(fmaf(fb0, fb0, fb1 * fb1)));

    const size_t base = (size_t)b * HW + y * WW + x;
    GFB[base] = (uint)f2bf_rne(fb0) | ((uint)f2bf_rne(fb1) << 16);
    GW[base]  = f2bf_rne(wv);
}

// ====== K2: convs + combine; float2 flow, 4-MFMA conv2, b64 combine ======
__global__ __launch_bounds__(256, 3)
void refine_kernel(const float* __restrict__ v0,
                   const uint* __restrict__ GFB,
                   const ushort* __restrict__ GW,
                   const uint4v* __restrict__ P,
                   float* __restrict__ out)
{
    __shared__ uint    g32[2 * FBWORDS];          // fb-pair plane | w-pair plane
    __shared__ float2v f2[FR * FPS2];             // flow tile, channels interleaved

    const int bx0 = blockIdx.x * TSX;
    const int by0 = blockIdx.y * TSY;
    const int b   = blockIdx.z;
    const int tid = threadIdx.x;
    const int w   = tid >> 6;
    const int L   = tid & 63;
    const int c   = L & 15;
    const int q   = L >> 4;

    const float*  v0b  = v0 + (size_t)b * 2 * HW;
    const uint*   GFBb = GFB + (size_t)b * HW;
    const ushort* GWb  = GW + (size_t)b * HW;

    // ---- per-lane params (loaded once) ----
    short8 a1h[2], a1l[2], a2[4];
    #pragma unroll
    for (int t = 0; t < 2; ++t) {
        a1h[t] = *reinterpret_cast<const short8*>(&P[(0 + t) * 64 + L]); keep(a1h[t]);
        a1l[t] = *reinterpret_cast<const short8*>(&P[(2 + t) * 64 + L]); keep(a1l[t]);
    }
    #pragma unroll
    for (int mt = 0; mt < 4; ++mt) {
        a2[mt] = *reinterpret_cast<const short8*>(&P[(4 + mt) * 64 + L]); keep(a2[mt]);
    }
    float4v bi1[2], bi2[4];
    #pragma unroll
    for (int t = 0; t < 2; ++t) {
        bi1[t] = *reinterpret_cast<const float4v*>(&P[(12 + t) * 64 + L]); keep(bi1[t]);
    }
    #pragma unroll
    for (int mt = 0; mt < 4; ++mt) {
        bi2[mt] = *reinterpret_cast<const float4v*>(&P[(14 + mt) * 64 + L]); keep(bi2[mt]);
    }
    int off1[4];
    {
        int4v o = *reinterpret_cast<const int4v*>(&P[18 * 64 + L]); keep(o);
        #pragma unroll
        for (int pl = 0; pl < 4; ++pl) off1[pl] = o[pl];
    }

    // ---- stage flow tile (36x36, halo 2), channels interleaved ----
    for (int i = tid; i < FR * FR; i += 256) {
        const int ly = i / FR, lx = i - (i / FR) * FR;
        const int y = by0 - 2 + ly, x = bx0 - 2 + lx;
        float f0 = 0.f, f1 = 0.f;
        if ((unsigned)y < HH && (unsigned)x < WW) {
            f0 = v0b[y * WW + x];
            f1 = v0b[HW + y * WW + x];
        }
        float2v p; p[0] = f0; p[1] = f1;
        f2[ly * FPS2 + lx] = p;
    }
    // ---- stage packed guidance: fb words + w pair-words ----
    for (int i = tid; i < GR * GR; i += 256) {
        const int r = i / GR, cc = i - (i / GR) * GR;
        const int y = by0 - 1 + r;
        const int xl = bx0 - 1 + cc;
        uint fbw = 0u, wl = 0u, wr = 0u;
        if ((unsigned)y < HH) {
            const size_t row = (size_t)y * WW;
            if ((unsigned)xl < WW) {
                fbw = GFBb[row + xl];
                wl  = GWb[row + xl];
            }
            const int xr = xl + 1;
            if ((unsigned)xr < WW) wr = GWb[row + xr];
        }
        g32[r * GS2 + cc]           = fbw;
        g32[FBWORDS + r * GS2 + cc] = wl | (wr << 16);
    }
    __syncthreads();

    // ---- 16 groups of 16 px per wave ----
    #pragma unroll 2
    for (int g = 0; g < 16; ++g) {
        const int py = 8 * w + (g >> 1);
        const int px = 16 * (g & 1) + c;
        const int gb = py * GS2 + px;

        // B1 frag: 4 u32 word gathers -> short8
        uint4v uw;
        #pragma unroll
        for (int pl = 0; pl < 4; ++pl) uw[pl] = g32[off1[pl] + gb];
        const short8 b1 = *reinterpret_cast<const short8*>(&uw);

        // conv3x3 GEMM (bf16 B, split A), bias in C
        float4v acc1_0 = bi1[0], acc1_1 = bi1[1];
        acc1_0 = MFMA16x32(a1l[0], b1, acc1_0);
        acc1_0 = MFMA16x32(a1h[0], b1, acc1_0);
        acc1_1 = MFMA16x32(a1l[1], b1, acc1_1);
        acc1_1 = MFMA16x32(a1h[1], b1, acc1_1);

        // ReLU + truncation bf16 (hi only; headroom verified) -> conv2 B frag
        short8 b2h;
        #pragma unroll
        for (int r = 0; r < 4; ++r) {
            const float h0 = fmaxf(acc1_0[r], 0.f);
            const float h1 = fmaxf(acc1_1[r], 0.f);
            b2h[r]     = (short)(fu(h0) >> 16);
            b2h[4 + r] = (short)(fu(h1) >> 16);
        }

        // conv1x1 GEMM via K-permuted 16x16x32, hi term only (4 MFMA)
        float4v acc2[4] = {bi2[0], bi2[1], bi2[2], bi2[3]};
        #pragma unroll
        for (int mt = 0; mt < 4; ++mt)
            acc2[mt] = MFMA16x32(a2[mt], b2h, acc2[mt]);

        // combine: 7 x ds_read_b64 (both channels per read)
        const int pyb   = py * FPS2 + px;
        const int base0 = pyb + q * FPS2;         // taps (q, 0..4)
        const int b4    = pyb + 4 * FPS2 + q;     // tap  (4, q)

        const float2v p0 = f2[base0];
        const float2v p1 = f2[base0 + 1];
        const float2v p2 = f2[base0 + 2];
        const float2v p3 = f2[base0 + 3];
        const float2v p4 = f2[base0 + 4];
        const float2v pb = f2[b4];
        const float2v pc = f2[base0 + 41];        // (4,4): kern==0 unless q==3

        float s0 = 0.f, s1 = 0.f;
        s0 = fmaf(acc2[0][0], p0[0], s0);  s1 = fmaf(acc2[2][0], p0[1], s1);
        s0 = fmaf(acc2[0][1], p1[0], s0);  s1 = fmaf(acc2[2][1], p1[1], s1);
        s0 = fmaf(acc2[0][2], p2[0], s0);  s1 = fmaf(acc2[2][2], p2[1], s1);
        s0 = fmaf(acc2[0][3], p3[0], s0);  s1 = fmaf(acc2[2][3], p3[1], s1);
        s0 = fmaf(acc2[1][0], p4[0], s0);  s1 = fmaf(acc2[3][0], p4[1], s1);
        s0 = fmaf(acc2[1][1], pb[0], s0);  s1 = fmaf(acc2[3][1], pb[1], s1);
        s0 = fmaf(acc2[1][2], pc[0], s0);  s1 = fmaf(acc2[3][2], pc[1], s1);

        s0 += __shfl_xor(s0, 16);
        s0 += __shfl_xor(s0, 32);
        s1 += __shfl_xor(s1, 16);
        s1 += __shfl_xor(s1, 32);

        if (q == 0) {
            const int y = by0 + py, x = bx0 + px;
            out[((size_t)b * 2 + 0) * HW + y * WW + x] = s0;
            out[((size_t)b * 2 + 1) * HW + y * WW + x] = s1;
        }
    }
}

extern "C" void kernel_launch(void* const* d_in, const int* in_sizes, int n_in,
                              void* d_out, int out_size, void* d_ws, size_t ws_size,
                              hipStream_t stream) {
    const float* v0 = (const float*)d_in[0];
    const float* v2 = (const float*)d_in[1];
    const float* w1 = (const float*)d_in[2];
    const float* b1 = (const float*)d_in[3];
    const float* w2 = (const float*)d_in[4];
    const float* b2 = (const float*)d_in[5];
    uint4v* ws  = (uint4v*)d_ws;
    uint*   GFB = (uint*)((char*)d_ws + WS_GOFF);
    ushort* GW  = (ushort*)((char*)d_ws + WS_WOFF);

    setup_params<<<1, 64, 0, stream>>>(w1, b1, w2, b2, ws);
    guidance_kernel<<<(BB * HW) / 256, 256, 0, stream>>>(v0, v2, GFB, GW);

    dim3 grid(WW / TSX, HH / TSY, BB);
    refine_kernel<<<grid, dim3(256, 1, 1), 0, stream>>>(v0, GFB, GW, ws, (float*)d_out);
}